// Round 2
// baseline (476.617 us; speedup 1.0000x reference)
//
#include <hip/hip_runtime.h>

// GestureRNN v2: DPP-rotation register-resident RNN. B=4096, T=512, IN=10, H=32.
// Lane j (0..31) of each 32-half owns hidden unit j; 2 batch elements per wave.
// Dot products over the lane-distributed h vectors are done with v_mov_b32_dpp
// row_ror:i rotations (16-lane rows) + one ds_swizzle(xor16) per h-vector per
// step for the cross-row half. Weight rows are pre-permuted at init to match
// the rotation order (rotation direction self-detected, so ror convention
// doesn't matter). No LDS round-trip, no barriers in the recurrence.

constexpr int T_  = 512;
constexpr int IN_ = 10;
constexpr int H_  = 32;
constexpr int NC_ = 9;

template <int I>
__device__ __forceinline__ float rotI(float v) {
    // row_ror:I  (I = 1..15), full row/bank masks, no bound ctrl
    return __int_as_float(
        __builtin_amdgcn_mov_dpp(__float_as_int(v), 0x120 + I, 0xF, 0xF, false));
}

__device__ __forceinline__ float swap16(float v) {
    // swap 16-lane rows within each 32-lane half: xor_mask=16, and_mask=0x1F
    return __int_as_float(__builtin_amdgcn_ds_swizzle(__float_as_int(v), 0x401F));
}

// 16-term rotated dot: term i pairs pre-permuted weight W[i] with ror:i of H.
// Split across two accumulators for ILP.
#define DOT16(aE, aO, W, H)                     \
    do {                                        \
        aE = fmaf((W)[0],  (H),         aE);    \
        aO = fmaf((W)[1],  rotI<1>(H),  aO);    \
        aE = fmaf((W)[2],  rotI<2>(H),  aE);    \
        aO = fmaf((W)[3],  rotI<3>(H),  aO);    \
        aE = fmaf((W)[4],  rotI<4>(H),  aE);    \
        aO = fmaf((W)[5],  rotI<5>(H),  aO);    \
        aE = fmaf((W)[6],  rotI<6>(H),  aE);    \
        aO = fmaf((W)[7],  rotI<7>(H),  aO);    \
        aE = fmaf((W)[8],  rotI<8>(H),  aE);    \
        aO = fmaf((W)[9],  rotI<9>(H),  aO);    \
        aE = fmaf((W)[10], rotI<10>(H), aE);    \
        aO = fmaf((W)[11], rotI<11>(H), aO);    \
        aE = fmaf((W)[12], rotI<12>(H), aE);    \
        aO = fmaf((W)[13], rotI<13>(H), aO);    \
        aE = fmaf((W)[14], rotI<14>(H), aE);    \
        aO = fmaf((W)[15], rotI<15>(H), aO);    \
    } while (0)

__global__ __launch_bounds__(64, 1) void gesture_rnn_kernel(
    const float* __restrict__ x,      // [B, T, IN]
    const float* __restrict__ W_ih0,  // [H, IN]
    const float* __restrict__ W_hh0,  // [H, H]
    const float* __restrict__ b_ih0,  // [H]
    const float* __restrict__ b_hh0,  // [H]
    const float* __restrict__ W_ih1,  // [H, H]
    const float* __restrict__ W_hh1,  // [H, H]
    const float* __restrict__ b_ih1,  // [H]
    const float* __restrict__ b_hh1,  // [H]
    const float* __restrict__ W_fc,   // [NC, H]
    const float* __restrict__ b_fc,   // [NC]
    float* __restrict__ out)          // [B, NC]
{
    const int lane = threadIdx.x;        // 0..63
    const int g    = lane >> 5;          // batch sub-group in wave
    const int j    = lane & 31;          // hidden unit index
    const int s    = j & 15;             // position within 16-row
    const int r    = (j >> 4) & 1;       // which 16-row of the half
    const long b   = (long)blockIdx.x * 2 + g;

    // --- self-detect DPP ror direction: idr = (s + d) & 15 ---
    const int idr = __builtin_amdgcn_mov_dpp(s, 0x121, 0xF, 0xF, false);
    const int d   = (idr - s) & 15;      // 1 or 15 (== -1 mod 16)

    // --- pre-permuted weight rows for hidden unit j ---
    float wx[IN_];
    float wa0[16], wb0[16];   // W_hh0: own-row / other-row rotation order
    float wa1[16], wb1[16];   // W_ih1
    float wa2[16], wb2[16];   // W_hh1
#pragma unroll
    for (int i = 0; i < IN_; ++i) wx[i] = W_ih0[j * IN_ + i];
#pragma unroll
    for (int i = 0; i < 16; ++i) {
        const int k  = (s + d * i) & 15;
        const int ko = 16 * r + k;         // own-row column
        const int kx = 16 * (1 - r) + k;   // other-row column
        wa0[i] = W_hh0[j * H_ + ko];  wb0[i] = W_hh0[j * H_ + kx];
        wa1[i] = W_ih1[j * H_ + ko];  wb1[i] = W_ih1[j * H_ + kx];
        wa2[i] = W_hh1[j * H_ + ko];  wb2[i] = W_hh1[j * H_ + kx];
    }
    const float bias0 = b_ih0[j] + b_hh0[j];
    const float bias1 = b_ih1[j] + b_hh1[j];

    // --- recurrent state, fully register-resident ---
    float h1 = 0.f, h1o = 0.f;   // own value + other-row copy
    float h2 = 0.f, h2o = 0.f;

    const float* xb = x + (size_t)b * T_ * IN_;
    float xv[IN_];
#pragma unroll
    for (int i = 0; i < IN_; i += 2) {
        float2 v = *(const float2*)(xb + i);
        xv[i] = v.x; xv[i + 1] = v.y;
    }

#pragma unroll 1
    for (int t = 0; t < T_; ++t) {
        // ---- layer-1 recurrent part first (independent of this step's h1) ----
        float cE = bias1, cO = 0.f, cP = 0.f, cQ = 0.f;
        DOT16(cE, cO, wa2, h2);
        DOT16(cP, cQ, wb2, h2o);

        // ---- layer-0: x-projection + recurrent ----
        float aX = bias0, aY = 0.f;
#pragma unroll
        for (int i = 0; i < IN_; i += 2) {
            aX = fmaf(wx[i],     xv[i],     aX);
            aY = fmaf(wx[i + 1], xv[i + 1], aY);
        }
        // prefetch next step's x while dots run
        if (t + 1 < T_) {
            const float* xn = xb + (size_t)(t + 1) * IN_;
#pragma unroll
            for (int i = 0; i < IN_; i += 2) {
                float2 v = *(const float2*)(xn + i);
                xv[i] = v.x; xv[i + 1] = v.y;
            }
        }
        float aE = 0.f, aO = 0.f, aP = 0.f, aQ = 0.f;
        DOT16(aE, aO, wa0, h1);
        DOT16(aP, aQ, wb0, h1o);
        const float h1n = fmaxf(((aX + aY) + (aE + aO)) + (aP + aQ), 0.f);

        // cross-row copy of the fresh h1 (DS latency overlapped with own-row dot)
        const float h1no = swap16(h1n);

        // ---- layer-1 input part ----
        DOT16(cE, cO, wa1, h1n);
        DOT16(cP, cQ, wb1, h1no);
        const float h2n  = fmaxf((cE + cO) + (cP + cQ), 0.f);
        const float h2no = swap16(h2n);   // latency hidden into next step

        h1 = h1n; h1o = h1no;
        h2 = h2n; h2o = h2no;
    }

    // ---- epilogue: gather h2 via tiny LDS, 9-way FC ----
    __shared__ float h2s[2][H_];
    h2s[g][j] = h2;
    __syncthreads();
    if (j < NC_) {
        float acc = b_fc[j];
#pragma unroll
        for (int k = 0; k < H_; ++k)
            acc = fmaf(W_fc[j * H_ + k], h2s[g][k], acc);
        out[b * NC_ + j] = acc;
    }
}

extern "C" void kernel_launch(void* const* d_in, const int* in_sizes, int n_in,
                              void* d_out, int out_size, void* d_ws, size_t ws_size,
                              hipStream_t stream) {
    const float* x     = (const float*)d_in[0];
    const float* W_ih0 = (const float*)d_in[1];
    const float* W_hh0 = (const float*)d_in[2];
    const float* b_ih0 = (const float*)d_in[3];
    const float* b_hh0 = (const float*)d_in[4];
    const float* W_ih1 = (const float*)d_in[5];
    const float* W_hh1 = (const float*)d_in[6];
    const float* b_ih1 = (const float*)d_in[7];
    const float* b_hh1 = (const float*)d_in[8];
    const float* W_fc  = (const float*)d_in[9];
    const float* b_fc  = (const float*)d_in[10];
    float* out = (float*)d_out;

    const int B = 4096;
    gesture_rnn_kernel<<<dim3(B / 2), dim3(64), 0, stream>>>(
        x, W_ih0, W_hh0, b_ih0, b_hh0, W_ih1, W_hh1, b_ih1, b_hh1,
        W_fc, b_fc, out);
}